// Round 8
// baseline (631.027 us; speedup 1.0000x reference)
//
#include <hip/hip_runtime.h>

typedef _Float16 f16;
typedef _Float16 f16x8 __attribute__((ext_vector_type(8)));
typedef _Float16 f16x4 __attribute__((ext_vector_type(4)));
typedef float f32x4 __attribute__((ext_vector_type(4)));

#define NR_ 16256
#define NO_ 128
#define NB_ 16

__device__ __forceinline__ f32x4 MF(f16x8 a, f16x8 b, f32x4 c) {
    return __builtin_amdgcn_mfma_f32_16x16x32_f16(a, b, c, 0, 0, 0);
}

// 16B-block XOR swizzle (r4-validated): element (r,o) of a [R][rs] f16 tile; rs mult of 8.
__device__ __forceinline__ int swzi(int r, int o, int rs) {
    int cb = (o >> 3) ^ (r & 7);
    return r * rs + (cb << 3) + (o & 7);
}

// ---------------- prep: fp32 -> f16 weight copies + er zero ----------------
__global__ void kprep(const float* __restrict__ rW0, const float* __restrict__ rW1,
                      const float* __restrict__ rW2,
                      f16* W0b, f16* W1b, f16* W2b, float* er)
{
    int i = blockIdx.x * 256 + threadIdx.x, n = gridDim.x * 256;
    for (int j = i; j < 40960; j += n) W0b[j] = (f16)rW0[j];
    for (int j = i; j < 65536; j += n) W1b[j] = (f16)rW1[j];
    for (int j = i; j < 32768; j += n) W2b[j] = (f16)rW2[j];
    for (int j = i; j < NB_ * 128 * 128; j += n) er[j] = 0.f;
}

// ---------------- OW precompute: OWsT[b][n][o] = sum_d O[b][o][d]*rW0[n][d] ----------------
__global__ __launch_bounds__(256)
void kow(const float* __restrict__ objects, const float* __restrict__ rW0,
         f16* __restrict__ OWsT, f16* __restrict__ OWrT)
{
    __shared__ float Os[8][64];
    const int b = blockIdx.x, oc = blockIdx.y;   // grid (16,16): 8 o-rows per block
    const int tid = threadIdx.x;
    for (int i = tid; i < 512; i += 256)
        Os[i >> 6][i & 63] = objects[((size_t)b * 128 + oc * 8 + (i >> 6)) * 64 + (i & 63)];
    __syncthreads();
    const int n = tid;                            // 0..255
    float as0=0,as1=0,as2=0,as3=0,as4=0,as5=0,as6=0,as7=0;
    float ar0=0,ar1=0,ar2=0,ar3=0,ar4=0,ar5=0,ar6=0,ar7=0;
    const float* w = rW0 + (size_t)n * 160;
    for (int d = 0; d < 64; d++) {
        float ws = w[d], wr = w[64 + d];
        as0 += Os[0][d]*ws; as1 += Os[1][d]*ws; as2 += Os[2][d]*ws; as3 += Os[3][d]*ws;
        as4 += Os[4][d]*ws; as5 += Os[5][d]*ws; as6 += Os[6][d]*ws; as7 += Os[7][d]*ws;
        ar0 += Os[0][d]*wr; ar1 += Os[1][d]*wr; ar2 += Os[2][d]*wr; ar3 += Os[3][d]*wr;
        ar4 += Os[4][d]*wr; ar5 += Os[5][d]*wr; ar6 += Os[6][d]*wr; ar7 += Os[7][d]*wr;
    }
    f16* ds = OWsT + ((size_t)b * 256 + n) * 128 + oc * 8;
    f16* dr = OWrT + ((size_t)b * 256 + n) * 128 + oc * 8;
    ds[0]=(f16)as0; ds[1]=(f16)as1; ds[2]=(f16)as2; ds[3]=(f16)as3;
    ds[4]=(f16)as4; ds[5]=(f16)as5; ds[6]=(f16)as6; ds[7]=(f16)as7;
    dr[0]=(f16)ar0; dr[1]=(f16)ar1; dr[2]=(f16)ar2; dr[3]=(f16)ar3;
    dr[4]=(f16)ar4; dr[5]=(f16)ar5; dr[6]=(f16)ar6; dr[7]=(f16)ar7;
}

// one MLP layer on swizzled LDS (r4-validated): M=64 rows, wave covers 32 cols
template<int KSTEPS, int K, int AS, int OS>
__device__ __forceinline__ void mlp64s(const f16* As, const f16* __restrict__ Wb,
                                       const float* __restrict__ bias, f16* Os,
                                       int n0, int l15, int lq)
{
    f32x4 acc[4][2] = {};
#pragma unroll
    for (int ks = 0; ks < KSTEPS; ks++) {
        f16x8 b0 = *(const f16x8*)(Wb + (size_t)(n0 + l15) * K + ks * 32 + (lq << 3));
        f16x8 b1 = *(const f16x8*)(Wb + (size_t)(n0 + 16 + l15) * K + ks * 32 + (lq << 3));
#pragma unroll
        for (int m = 0; m < 4; m++) {
            f16x8 af = *(const f16x8*)(As + swzi(m * 16 + l15, ks * 32 + (lq << 3), AS));
            acc[m][0] = MF(af, b0, acc[m][0]);
            acc[m][1] = MF(af, b1, acc[m][1]);
        }
    }
    float bv0 = bias[n0 + l15], bv1 = bias[n0 + 16 + l15];
#pragma unroll
    for (int m = 0; m < 4; m++) {
#pragma unroll
        for (int q = 0; q < 4; q++) {
            int row = m * 16 + (lq << 2) + q;
            Os[swzi(row, n0 + l15, OS)]      = (f16)fmaxf(acc[m][0][q] + bv0, 0.f);
            Os[swzi(row, n0 + 16 + l15, OS)] = (f16)fmaxf(acc[m][1][q] + bv1, 0.f);
        }
    }
}

// ------- fused relational kernel: K=288 fused L1 + L2 + L3 + scatter; 80KB LDS, 2 blk/CU -------
__global__ __launch_bounds__(512, 4)
void krel7(const float* __restrict__ SR, const float* __restrict__ RRg,
           const float* __restrict__ RI,
           const f16* __restrict__ W0b, const f16* __restrict__ W1b,
           const f16* __restrict__ W2b,
           const float* __restrict__ rb0, const float* __restrict__ rb1,
           const float* __restrict__ rb2,
           const f16* __restrict__ OWsT, const f16* __restrict__ OWrT,
           float* __restrict__ er)
{
    __shared__ __align__(16) char smem[81920];
    f16* SRt = (f16*)(smem);            // [64][128] swz  (dead after L1)
    f16* RRt = (f16*)(smem + 16384);    // [64][128] swz  (dead after L1)
    f16* RRs = (f16*)(smem + 32768);    // [128][64] swz  (live until scatter)
    f16* h1s = (f16*)(smem + 49152);    // [64][256] swz  (dead after L2)
    f16* h2s = (f16*)(smem);            // [64][256] swz  aliases SRt+RRt
    f16* EtS = (f16*)(smem + 49152);    // [128][64] swz  aliases h1s

    const int b = blockIdx.y;
    const int grp = blockIdx.x;          // 32 groups
    const int tid = threadIdx.x;
    const int lane = tid & 63;
    const int wave = tid >> 6;
    const int l15 = lane & 15;
    const int lq = lane >> 4;
    const int k = tid & 7;

    f32x4 asc[8] = {};   // scatter accum: o-frag = wave, e-frags 0..7
    const size_t sbase = (size_t)b * NO_ * NR_;

    for (int t = grp; t < 254; t += 32) {
        const int r0 = t * 64;

        // ---- stage SR^T, RR^T ([r][o] swz) and RR ([o][r] swz) — conflict-free ----
#pragma unroll
        for (int half = 0; half < 2; half++) {
            int o = (tid >> 3) + (half << 6);
            const float* ps = SR + sbase + (size_t)o * NR_ + r0 + k;
            const float* pr = RRg + sbase + (size_t)o * NR_ + r0 + k;
#pragma unroll
            for (int j = 0; j < 8; j++) {
                float sv = ps[8 * j];
                float rv = pr[8 * j];
                int r = k + 8 * j;
                SRt[swzi(r, o, 128)] = (f16)sv;
                RRt[swzi(r, o, 128)] = (f16)rv;
                RRs[swzi(o, r, 64)]  = (f16)rv;
            }
        }
        __syncthreads();

        // ---- fused L1: h1 = relu(SR^T·OWs + RR^T·OWr + RI·W0i^T + b0), K=288 ----
        {
            f32x4 acc[4][2] = {};
            const int n0 = wave * 32;
            const f16* Bs = OWsT + ((size_t)b * 256 + n0 + l15) * 128 + (lq << 3);
            const f16* Br = OWrT + ((size_t)b * 256 + n0 + l15) * 128 + (lq << 3);
#pragma unroll
            for (int ks = 0; ks < 4; ks++) {
                f16x8 b0 = *(const f16x8*)(Bs + (ks << 5));
                f16x8 b1 = *(const f16x8*)(Bs + (ks << 5) + 2048);   // +16 rows * 128
#pragma unroll
                for (int m = 0; m < 4; m++) {
                    f16x8 af = *(const f16x8*)(SRt + swzi(m * 16 + l15, (ks << 5) + (lq << 3), 128));
                    acc[m][0] = MF(af, b0, acc[m][0]);
                    acc[m][1] = MF(af, b1, acc[m][1]);
                }
            }
#pragma unroll
            for (int ks = 0; ks < 4; ks++) {
                f16x8 b0 = *(const f16x8*)(Br + (ks << 5));
                f16x8 b1 = *(const f16x8*)(Br + (ks << 5) + 2048);
#pragma unroll
                for (int m = 0; m < 4; m++) {
                    f16x8 af = *(const f16x8*)(RRt + swzi(m * 16 + l15, (ks << 5) + (lq << 3), 128));
                    acc[m][0] = MF(af, b0, acc[m][0]);
                    acc[m][1] = MF(af, b1, acc[m][1]);
                }
            }
            {   // RI segment, K=32, A read directly from global f32
                f16x8 b0 = *(const f16x8*)(W0b + (size_t)(n0 + l15) * 160 + 128 + (lq << 3));
                f16x8 b1 = *(const f16x8*)(W0b + (size_t)(n0 + 16 + l15) * 160 + 128 + (lq << 3));
#pragma unroll
                for (int m = 0; m < 4; m++) {
                    const float* pri = RI + ((size_t)b * NR_ + r0 + m * 16 + l15) * 32 + (lq << 3);
                    float4 v0 = *(const float4*)pri;
                    float4 v1 = *(const float4*)(pri + 4);
                    f16x8 af;
                    af[0]=(f16)v0.x; af[1]=(f16)v0.y; af[2]=(f16)v0.z; af[3]=(f16)v0.w;
                    af[4]=(f16)v1.x; af[5]=(f16)v1.y; af[6]=(f16)v1.z; af[7]=(f16)v1.w;
                    acc[m][0] = MF(af, b0, acc[m][0]);
                    acc[m][1] = MF(af, b1, acc[m][1]);
                }
            }
            float bv0 = rb0[n0 + l15], bv1 = rb0[n0 + 16 + l15];
#pragma unroll
            for (int m = 0; m < 4; m++) {
#pragma unroll
                for (int q = 0; q < 4; q++) {
                    int row = m * 16 + (lq << 2) + q;
                    h1s[swzi(row, n0 + l15, 256)]      = (f16)fmaxf(acc[m][0][q] + bv0, 0.f);
                    h1s[swzi(row, n0 + 16 + l15, 256)] = (f16)fmaxf(acc[m][1][q] + bv1, 0.f);
                }
            }
        }
        __syncthreads();

        mlp64s<8, 256, 256, 256>(h1s, W1b, rb1, h2s, wave * 32, l15, lq);
        __syncthreads();

        // ---- layer3 -> effects^T [e][r] in LDS (swizzled) ----
        {
            const int e = (wave << 4) + l15;
            f32x4 acc[4] = {};
#pragma unroll
            for (int ks = 0; ks < 8; ks++) {
                f16x8 bf = *(const f16x8*)(W2b + (size_t)e * 256 + (ks << 5) + (lq << 3));
#pragma unroll
                for (int m = 0; m < 4; m++) {
                    f16x8 af = *(const f16x8*)(h2s + swzi(m * 16 + l15, (ks << 5) + (lq << 3), 256));
                    acc[m] = MF(af, bf, acc[m]);
                }
            }
            float bv = rb2[e];
#pragma unroll
            for (int m = 0; m < 4; m++) {
                f16x4 pk;
#pragma unroll
                for (int q = 0; q < 4; q++) pk[q] = (f16)fmaxf(acc[m][q] + bv, 0.f);
                *(f16x4*)(EtS + swzi(e, (m << 4) + (lq << 2), 64)) = pk;
            }
        }
        __syncthreads();

        // ---- scatter partial: asc[nf] += RRs(o rows) x EtS(e rows), K = 64 ----
        {
            const int ow = wave << 4;
#pragma unroll
            for (int ks = 0; ks < 2; ks++) {
                f16x8 af = *(const f16x8*)(RRs + swzi(ow + l15, (ks << 5) + (lq << 3), 64));
#pragma unroll
                for (int nf = 0; nf < 8; nf++) {
                    f16x8 bf = *(const f16x8*)(EtS + swzi((nf << 4) + l15, (ks << 5) + (lq << 3), 64));
                    asc[nf] = MF(af, bf, asc[nf]);
                }
            }
        }
        __syncthreads();   // staging buffers free for next iteration
    }

    // ---- commit scatter partials ----
    float* dst = er + ((size_t)b << 14);
#pragma unroll
    for (int nf = 0; nf < 8; nf++) {
        int e = (nf << 4) + l15;
#pragma unroll
        for (int q = 0; q < 4; q++) {
            int o = (wave << 4) + (lq << 2) + q;
            atomicAdd(dst + (size_t)o * 128 + e, asc[nf][q]);
        }
    }
}

// ---------------- object MLP, all-f32 VALU, f32 output ----------------
__global__ __launch_bounds__(256)
void kobj32(const float* __restrict__ objects, const float* __restrict__ er,
            const float* __restrict__ oW0, const float* __restrict__ oW1,
            const float* __restrict__ oW2,
            const float* __restrict__ ob0, const float* __restrict__ ob1,
            const float* __restrict__ ob2, float* __restrict__ out)
{
    __shared__ float ys[8][192];
    __shared__ float h1[8][256];
    __shared__ float h2[8][128];
    const int r0 = blockIdx.x * 8;        // 256 blocks x 8 rows = 2048 rows (b*128+o)
    const int tid = threadIdx.x;

    for (int c = tid; c < 8 * 192; c += 256) {
        int rr = c / 192, kk = c % 192;
        ys[rr][kk] = (kk < 64) ? objects[(size_t)(r0 + rr) * 64 + kk]
                               : er[(size_t)(r0 + rr) * 128 + (kk - 64)];
    }
    __syncthreads();
    for (int c = tid; c < 8 * 256; c += 256) {   // layer1: K=192, N=256
        int rr = c >> 8, n = c & 255;
        const float* w = oW0 + (size_t)n * 192;
        float s = ob0[n];
        for (int kk = 0; kk < 192; kk++) s += ys[rr][kk] * w[kk];
        h1[rr][n] = fmaxf(s, 0.f);
    }
    __syncthreads();
    for (int c = tid; c < 8 * 128; c += 256) {   // layer2: K=256, N=128
        int rr = c >> 7, n = c & 127;
        const float* w = oW1 + (size_t)n * 256;
        float s = ob1[n];
        for (int kk = 0; kk < 256; kk++) s += h1[rr][kk] * w[kk];
        h2[rr][n] = fmaxf(s, 0.f);
    }
    __syncthreads();
    for (int c = tid; c < 24; c += 256) {        // layer3: N=3
        int rr = c / 3, j = c % 3;
        const float* w = oW2 + j * 128;
        float s = ob2[j];
        for (int kk = 0; kk < 128; kk++) s += h2[rr][kk] * w[kk];
        out[(size_t)(r0 + rr) * 3 + j] = s;
    }
}

extern "C" void kernel_launch(void* const* d_in, const int* in_sizes, int n_in,
                              void* d_out, int out_size, void* d_ws, size_t ws_size,
                              hipStream_t stream)
{
    (void)in_sizes; (void)n_in; (void)out_size; (void)ws_size;
    const float* objects = (const float*)d_in[0];
    const float* SR  = (const float*)d_in[1];
    const float* RRg = (const float*)d_in[2];
    const float* RI  = (const float*)d_in[3];
    const float* rW0 = (const float*)d_in[4];
    const float* rb0 = (const float*)d_in[5];
    const float* rW1 = (const float*)d_in[6];
    const float* rb1 = (const float*)d_in[7];
    const float* rW2 = (const float*)d_in[8];
    const float* rb2 = (const float*)d_in[9];
    const float* oW0 = (const float*)d_in[10];
    const float* ob0 = (const float*)d_in[11];
    const float* oW1 = (const float*)d_in[12];
    const float* ob1 = (const float*)d_in[13];
    const float* oW2 = (const float*)d_in[14];
    const float* ob2 = (const float*)d_in[15];

    char* ws = (char*)d_ws;
    f16* W0b  = (f16*)(ws + 0);            // 81920 B
    f16* W1b  = (f16*)(ws + 81920);        // 131072 B
    f16* W2b  = (f16*)(ws + 212992);       // 65536 B
    f16* OWsT = (f16*)(ws + 278528);       // 1048576 B
    f16* OWrT = (f16*)(ws + 1327104);      // 1048576 B
    float* er = (float*)(ws + 2375680);    // 1048576 B  (total ~3.4 MB)

    hipLaunchKernelGGL(kprep, dim3(512), dim3(256), 0, stream,
                       rW0, rW1, rW2, W0b, W1b, W2b, er);
    hipLaunchKernelGGL(kow, dim3(16, 16), dim3(256), 0, stream,
                       objects, rW0, OWsT, OWrT);
    hipLaunchKernelGGL(krel7, dim3(32, 16), dim3(512), 0, stream,
                       SR, RRg, RI, W0b, W1b, W2b, rb0, rb1, rb2, OWsT, OWrT, er);
    hipLaunchKernelGGL(kobj32, dim3(256), dim3(256), 0, stream,
                       objects, er, oW0, oW1, oW2, ob0, ob1, ob2, (float*)d_out);
}

// Round 9
// 520.909 us; speedup vs baseline: 1.2114x; 1.2114x over previous
//
#include <hip/hip_runtime.h>

typedef _Float16 f16;
typedef _Float16 f16x8 __attribute__((ext_vector_type(8)));
typedef _Float16 f16x4 __attribute__((ext_vector_type(4)));
typedef float f32x4 __attribute__((ext_vector_type(4)));

#define NR_ 16256
#define NO_ 128
#define NB_ 16

__device__ __forceinline__ f32x4 MF(f16x8 a, f16x8 b, f32x4 c) {
    return __builtin_amdgcn_mfma_f32_16x16x32_f16(a, b, c, 0, 0, 0);
}

// 16B-block XOR swizzle (r4-validated): element (r,o) of a [R][rs] f16 tile; rs mult of 8.
__device__ __forceinline__ int swzi(int r, int o, int rs) {
    int cb = (o >> 3) ^ (r & 7);
    return r * rs + (cb << 3) + (o & 7);
}

// ---------------- prep: fp32 -> f16 weight copies + er zero ----------------
__global__ void kprep(const float* __restrict__ rW0, const float* __restrict__ rW1,
                      const float* __restrict__ rW2,
                      f16* W0b, f16* W1b, f16* W2b, float* er)
{
    int i = blockIdx.x * 256 + threadIdx.x, n = gridDim.x * 256;
    for (int j = i; j < 40960; j += n) W0b[j] = (f16)rW0[j];
    for (int j = i; j < 65536; j += n) W1b[j] = (f16)rW1[j];
    for (int j = i; j < 32768; j += n) W2b[j] = (f16)rW2[j];
    for (int j = i; j < NB_ * 128 * 128; j += n) er[j] = 0.f;
}

// ---------------- OW precompute: OWsT[b][n][o] = sum_d O[b][o][d]*rW0[n][d] ----------------
__global__ __launch_bounds__(256)
void kow(const float* __restrict__ objects, const float* __restrict__ rW0,
         f16* __restrict__ OWsT, f16* __restrict__ OWrT)
{
    __shared__ float Os[8][64];
    const int b = blockIdx.x, oc = blockIdx.y;   // grid (16,16): 8 o-rows per block
    const int tid = threadIdx.x;
    for (int i = tid; i < 512; i += 256)
        Os[i >> 6][i & 63] = objects[((size_t)b * 128 + oc * 8 + (i >> 6)) * 64 + (i & 63)];
    __syncthreads();
    const int n = tid;                            // 0..255
    float as0=0,as1=0,as2=0,as3=0,as4=0,as5=0,as6=0,as7=0;
    float ar0=0,ar1=0,ar2=0,ar3=0,ar4=0,ar5=0,ar6=0,ar7=0;
    const float* w = rW0 + (size_t)n * 160;
    for (int d = 0; d < 64; d++) {
        float ws = w[d], wr = w[64 + d];
        as0 += Os[0][d]*ws; as1 += Os[1][d]*ws; as2 += Os[2][d]*ws; as3 += Os[3][d]*ws;
        as4 += Os[4][d]*ws; as5 += Os[5][d]*ws; as6 += Os[6][d]*ws; as7 += Os[7][d]*ws;
        ar0 += Os[0][d]*wr; ar1 += Os[1][d]*wr; ar2 += Os[2][d]*wr; ar3 += Os[3][d]*wr;
        ar4 += Os[4][d]*wr; ar5 += Os[5][d]*wr; ar6 += Os[6][d]*wr; ar7 += Os[7][d]*wr;
    }
    f16* ds = OWsT + ((size_t)b * 256 + n) * 128 + oc * 8;
    f16* dr = OWrT + ((size_t)b * 256 + n) * 128 + oc * 8;
    ds[0]=(f16)as0; ds[1]=(f16)as1; ds[2]=(f16)as2; ds[3]=(f16)as3;
    ds[4]=(f16)as4; ds[5]=(f16)as5; ds[6]=(f16)as6; ds[7]=(f16)as7;
    dr[0]=(f16)ar0; dr[1]=(f16)ar1; dr[2]=(f16)ar2; dr[3]=(f16)ar3;
    dr[4]=(f16)ar4; dr[5]=(f16)ar5; dr[6]=(f16)ar6; dr[7]=(f16)ar7;
}

// one MLP layer on swizzled LDS (r4-validated): M=64 rows, wave covers 32 cols
template<int KSTEPS, int K, int AS, int OS>
__device__ __forceinline__ void mlp64s(const f16* As, const f16* __restrict__ Wb,
                                       const float* __restrict__ bias, f16* Os,
                                       int n0, int l15, int lq)
{
    f32x4 acc[4][2] = {};
#pragma unroll
    for (int ks = 0; ks < KSTEPS; ks++) {
        f16x8 b0 = *(const f16x8*)(Wb + (size_t)(n0 + l15) * K + ks * 32 + (lq << 3));
        f16x8 b1 = *(const f16x8*)(Wb + (size_t)(n0 + 16 + l15) * K + ks * 32 + (lq << 3));
#pragma unroll
        for (int m = 0; m < 4; m++) {
            f16x8 af = *(const f16x8*)(As + swzi(m * 16 + l15, ks * 32 + (lq << 3), AS));
            acc[m][0] = MF(af, b0, acc[m][0]);
            acc[m][1] = MF(af, b1, acc[m][1]);
        }
    }
    float bv0 = bias[n0 + l15], bv1 = bias[n0 + 16 + l15];
#pragma unroll
    for (int m = 0; m < 4; m++) {
#pragma unroll
        for (int q = 0; q < 4; q++) {
            int row = m * 16 + (lq << 2) + q;
            Os[swzi(row, n0 + l15, OS)]      = (f16)fmaxf(acc[m][0][q] + bv0, 0.f);
            Os[swzi(row, n0 + 16 + l15, OS)] = (f16)fmaxf(acc[m][1][q] + bv1, 0.f);
        }
    }
}

// ------- fused relational kernel: K=288 fused L1 + L2 + L3 + scatter; 80KB LDS, 2 blk/CU -------
__global__ __launch_bounds__(512, 2)
void krel8(const float* __restrict__ SR, const float* __restrict__ RRg,
           const float* __restrict__ RI,
           const f16* __restrict__ W0b, const f16* __restrict__ W1b,
           const f16* __restrict__ W2b,
           const float* __restrict__ rb0, const float* __restrict__ rb1,
           const float* __restrict__ rb2,
           const f16* __restrict__ OWsT, const f16* __restrict__ OWrT,
           float* __restrict__ er)
{
    __shared__ __align__(16) char smem[81920];
    f16* SRt = (f16*)(smem);            // [64][128] swz  (dead after L1)
    f16* RRt = (f16*)(smem + 16384);    // [64][128] swz  (dead after L1)
    f16* RRs = (f16*)(smem + 32768);    // [128][64] swz  (live until scatter)
    f16* h1s = (f16*)(smem + 49152);    // [64][256] swz  (dead after L2)
    f16* h2s = (f16*)(smem);            // [64][256] swz  aliases SRt+RRt
    f16* EtS = (f16*)(smem + 49152);    // [128][64] swz  aliases h1s

    const int b = blockIdx.y;
    const int grp = blockIdx.x;          // 32 groups
    const int tid = threadIdx.x;
    const int lane = tid & 63;
    const int wave = tid >> 6;
    const int l15 = lane & 15;
    const int lq = lane >> 4;
    const int k = tid & 7;

    f32x4 asc[8] = {};   // scatter accum: o-frag = wave, e-frags 0..7
    const size_t sbase = (size_t)b * NO_ * NR_;

    for (int t = grp; t < 254; t += 32) {
        const int r0 = t * 64;

        // ---- stage SR^T, RR^T ([r][o] swz) and RR ([o][r] swz) — conflict-free ----
#pragma unroll
        for (int half = 0; half < 2; half++) {
            int o = (tid >> 3) + (half << 6);
            const float* ps = SR + sbase + (size_t)o * NR_ + r0 + k;
            const float* pr = RRg + sbase + (size_t)o * NR_ + r0 + k;
#pragma unroll
            for (int j = 0; j < 8; j++) {
                float sv = ps[8 * j];
                float rv = pr[8 * j];
                int r = k + 8 * j;
                SRt[swzi(r, o, 128)] = (f16)sv;
                RRt[swzi(r, o, 128)] = (f16)rv;
                RRs[swzi(o, r, 64)]  = (f16)rv;
            }
        }
        __syncthreads();

        // ---- fused L1: h1 = relu(SR^T·OWs + RR^T·OWr + RI·W0i^T + b0), K=288 ----
        {
            f32x4 acc[4][2] = {};
            const int n0 = wave * 32;
            const f16* Bs = OWsT + ((size_t)b * 256 + n0 + l15) * 128 + (lq << 3);
            const f16* Br = OWrT + ((size_t)b * 256 + n0 + l15) * 128 + (lq << 3);
#pragma unroll
            for (int ks = 0; ks < 4; ks++) {
                f16x8 b0 = *(const f16x8*)(Bs + (ks << 5));
                f16x8 b1 = *(const f16x8*)(Bs + (ks << 5) + 2048);   // +16 rows * 128
#pragma unroll
                for (int m = 0; m < 4; m++) {
                    f16x8 af = *(const f16x8*)(SRt + swzi(m * 16 + l15, (ks << 5) + (lq << 3), 128));
                    acc[m][0] = MF(af, b0, acc[m][0]);
                    acc[m][1] = MF(af, b1, acc[m][1]);
                }
            }
#pragma unroll
            for (int ks = 0; ks < 4; ks++) {
                f16x8 b0 = *(const f16x8*)(Br + (ks << 5));
                f16x8 b1 = *(const f16x8*)(Br + (ks << 5) + 2048);
#pragma unroll
                for (int m = 0; m < 4; m++) {
                    f16x8 af = *(const f16x8*)(RRt + swzi(m * 16 + l15, (ks << 5) + (lq << 3), 128));
                    acc[m][0] = MF(af, b0, acc[m][0]);
                    acc[m][1] = MF(af, b1, acc[m][1]);
                }
            }
            {   // RI segment, K=32, A read directly from global f32
                f16x8 b0 = *(const f16x8*)(W0b + (size_t)(n0 + l15) * 160 + 128 + (lq << 3));
                f16x8 b1 = *(const f16x8*)(W0b + (size_t)(n0 + 16 + l15) * 160 + 128 + (lq << 3));
#pragma unroll
                for (int m = 0; m < 4; m++) {
                    const float* pri = RI + ((size_t)b * NR_ + r0 + m * 16 + l15) * 32 + (lq << 3);
                    float4 v0 = *(const float4*)pri;
                    float4 v1 = *(const float4*)(pri + 4);
                    f16x8 af;
                    af[0]=(f16)v0.x; af[1]=(f16)v0.y; af[2]=(f16)v0.z; af[3]=(f16)v0.w;
                    af[4]=(f16)v1.x; af[5]=(f16)v1.y; af[6]=(f16)v1.z; af[7]=(f16)v1.w;
                    acc[m][0] = MF(af, b0, acc[m][0]);
                    acc[m][1] = MF(af, b1, acc[m][1]);
                }
            }
            float bv0 = rb0[n0 + l15], bv1 = rb0[n0 + 16 + l15];
#pragma unroll
            for (int m = 0; m < 4; m++) {
#pragma unroll
                for (int q = 0; q < 4; q++) {
                    int row = m * 16 + (lq << 2) + q;
                    h1s[swzi(row, n0 + l15, 256)]      = (f16)fmaxf(acc[m][0][q] + bv0, 0.f);
                    h1s[swzi(row, n0 + 16 + l15, 256)] = (f16)fmaxf(acc[m][1][q] + bv1, 0.f);
                }
            }
        }
        __syncthreads();

        mlp64s<8, 256, 256, 256>(h1s, W1b, rb1, h2s, wave * 32, l15, lq);
        __syncthreads();

        // ---- layer3 -> effects^T [e][r] in LDS (swizzled) ----
        {
            const int e = (wave << 4) + l15;
            f32x4 acc[4] = {};
#pragma unroll
            for (int ks = 0; ks < 8; ks++) {
                f16x8 bf = *(const f16x8*)(W2b + (size_t)e * 256 + (ks << 5) + (lq << 3));
#pragma unroll
                for (int m = 0; m < 4; m++) {
                    f16x8 af = *(const f16x8*)(h2s + swzi(m * 16 + l15, (ks << 5) + (lq << 3), 256));
                    acc[m] = MF(af, bf, acc[m]);
                }
            }
            float bv = rb2[e];
#pragma unroll
            for (int m = 0; m < 4; m++) {
                f16x4 pk;
#pragma unroll
                for (int q = 0; q < 4; q++) pk[q] = (f16)fmaxf(acc[m][q] + bv, 0.f);
                *(f16x4*)(EtS + swzi(e, (m << 4) + (lq << 2), 64)) = pk;
            }
        }
        __syncthreads();

        // ---- scatter partial: asc[nf] += RRs(o rows) x EtS(e rows), K = 64 ----
        {
            const int ow = wave << 4;
#pragma unroll
            for (int ks = 0; ks < 2; ks++) {
                f16x8 af = *(const f16x8*)(RRs + swzi(ow + l15, (ks << 5) + (lq << 3), 64));
#pragma unroll
                for (int nf = 0; nf < 8; nf++) {
                    f16x8 bf = *(const f16x8*)(EtS + swzi((nf << 4) + l15, (ks << 5) + (lq << 3), 64));
                    asc[nf] = MF(af, bf, asc[nf]);
                }
            }
        }
        __syncthreads();   // staging buffers free for next iteration
    }

    // ---- commit scatter partials ----
    float* dst = er + ((size_t)b << 14);
#pragma unroll
    for (int nf = 0; nf < 8; nf++) {
        int e = (nf << 4) + l15;
#pragma unroll
        for (int q = 0; q < 4; q++) {
            int o = (wave << 4) + (lq << 2) + q;
            atomicAdd(dst + (size_t)o * 128 + e, asc[nf][q]);
        }
    }
}

// ---------------- object MLP, all-f32 VALU, f32 output ----------------
__global__ __launch_bounds__(256)
void kobj32(const float* __restrict__ objects, const float* __restrict__ er,
            const float* __restrict__ oW0, const float* __restrict__ oW1,
            const float* __restrict__ oW2,
            const float* __restrict__ ob0, const float* __restrict__ ob1,
            const float* __restrict__ ob2, float* __restrict__ out)
{
    __shared__ float ys[8][192];
    __shared__ float h1[8][256];
    __shared__ float h2[8][128];
    const int r0 = blockIdx.x * 8;        // 256 blocks x 8 rows = 2048 rows (b*128+o)
    const int tid = threadIdx.x;

    for (int c = tid; c < 8 * 192; c += 256) {
        int rr = c / 192, kk = c % 192;
        ys[rr][kk] = (kk < 64) ? objects[(size_t)(r0 + rr) * 64 + kk]
                               : er[(size_t)(r0 + rr) * 128 + (kk - 64)];
    }
    __syncthreads();
    for (int c = tid; c < 8 * 256; c += 256) {   // layer1: K=192, N=256
        int rr = c >> 8, n = c & 255;
        const float* w = oW0 + (size_t)n * 192;
        float s = ob0[n];
        for (int kk = 0; kk < 192; kk++) s += ys[rr][kk] * w[kk];
        h1[rr][n] = fmaxf(s, 0.f);
    }
    __syncthreads();
    for (int c = tid; c < 8 * 128; c += 256) {   // layer2: K=256, N=128
        int rr = c >> 7, n = c & 127;
        const float* w = oW1 + (size_t)n * 256;
        float s = ob1[n];
        for (int kk = 0; kk < 256; kk++) s += h1[rr][kk] * w[kk];
        h2[rr][n] = fmaxf(s, 0.f);
    }
    __syncthreads();
    for (int c = tid; c < 24; c += 256) {        // layer3: N=3
        int rr = c / 3, j = c % 3;
        const float* w = oW2 + j * 128;
        float s = ob2[j];
        for (int kk = 0; kk < 128; kk++) s += h2[rr][kk] * w[kk];
        out[(size_t)(r0 + rr) * 3 + j] = s;
    }
}

extern "C" void kernel_launch(void* const* d_in, const int* in_sizes, int n_in,
                              void* d_out, int out_size, void* d_ws, size_t ws_size,
                              hipStream_t stream)
{
    (void)in_sizes; (void)n_in; (void)out_size; (void)ws_size;
    const float* objects = (const float*)d_in[0];
    const float* SR  = (const float*)d_in[1];
    const float* RRg = (const float*)d_in[2];
    const float* RI  = (const float*)d_in[3];
    const float* rW0 = (const float*)d_in[4];
    const float* rb0 = (const float*)d_in[5];
    const float* rW1 = (const float*)d_in[6];
    const float* rb1 = (const float*)d_in[7];
    const float* rW2 = (const float*)d_in[8];
    const float* rb2 = (const float*)d_in[9];
    const float* oW0 = (const float*)d_in[10];
    const float* ob0 = (const float*)d_in[11];
    const float* oW1 = (const float*)d_in[12];
    const float* ob1 = (const float*)d_in[13];
    const float* oW2 = (const float*)d_in[14];
    const float* ob2 = (const float*)d_in[15];

    char* ws = (char*)d_ws;
    f16* W0b  = (f16*)(ws + 0);            // 81920 B
    f16* W1b  = (f16*)(ws + 81920);        // 131072 B
    f16* W2b  = (f16*)(ws + 212992);       // 65536 B
    f16* OWsT = (f16*)(ws + 278528);       // 1048576 B
    f16* OWrT = (f16*)(ws + 1327104);      // 1048576 B
    float* er = (float*)(ws + 2375680);    // 1048576 B  (total ~3.4 MB)

    hipLaunchKernelGGL(kprep, dim3(512), dim3(256), 0, stream,
                       rW0, rW1, rW2, W0b, W1b, W2b, er);
    hipLaunchKernelGGL(kow, dim3(16, 16), dim3(256), 0, stream,
                       objects, rW0, OWsT, OWrT);
    hipLaunchKernelGGL(krel8, dim3(32, 16), dim3(512), 0, stream,
                       SR, RRg, RI, W0b, W1b, W2b, rb0, rb1, rb2, OWsT, OWrT, er);
    hipLaunchKernelGGL(kobj32, dim3(256), dim3(256), 0, stream,
                       objects, er, oW0, oW1, oW2, ob0, ob1, ob2, (float*)d_out);
}

// Round 10
// 468.631 us; speedup vs baseline: 1.3465x; 1.1116x over previous
//
#include <hip/hip_runtime.h>

typedef _Float16 f16;
typedef _Float16 f16x8 __attribute__((ext_vector_type(8)));
typedef _Float16 f16x4 __attribute__((ext_vector_type(4)));
typedef float f32x4 __attribute__((ext_vector_type(4)));

#define NR_ 16256
#define NO_ 128
#define NB_ 16

__device__ __forceinline__ f32x4 MF(f16x8 a, f16x8 b, f32x4 c) {
    return __builtin_amdgcn_mfma_f32_16x16x32_f16(a, b, c, 0, 0, 0);
}

// 16B-block XOR swizzle (r4-validated): element (r,o) of a [R][rs] f16 tile; rs mult of 8.
__device__ __forceinline__ int swzi(int r, int o, int rs) {
    int cb = (o >> 3) ^ (r & 7);
    return r * rs + (cb << 3) + (o & 7);
}

// ---------------- prep: fp32 -> f16 weight copies + er zero ----------------
__global__ void kprep(const float* __restrict__ rW0, const float* __restrict__ rW1,
                      const float* __restrict__ rW2,
                      f16* W0b, f16* W1b, f16* W2b, float* er)
{
    int i = blockIdx.x * 256 + threadIdx.x, n = gridDim.x * 256;
    for (int j = i; j < 40960; j += n) W0b[j] = (f16)rW0[j];
    for (int j = i; j < 65536; j += n) W1b[j] = (f16)rW1[j];
    for (int j = i; j < 32768; j += n) W2b[j] = (f16)rW2[j];
    for (int j = i; j < NB_ * 128 * 128; j += n) er[j] = 0.f;
}

// ---------------- OW precompute: OWsT[b][n][o] = sum_d O[b][o][d]*rW0[n][d] ----------------
__global__ __launch_bounds__(256)
void kow(const float* __restrict__ objects, const float* __restrict__ rW0,
         f16* __restrict__ OWsT, f16* __restrict__ OWrT)
{
    __shared__ float Os[8][64];
    const int b = blockIdx.x, oc = blockIdx.y;   // grid (16,16): 8 o-rows per block
    const int tid = threadIdx.x;
    for (int i = tid; i < 512; i += 256)
        Os[i >> 6][i & 63] = objects[((size_t)b * 128 + oc * 8 + (i >> 6)) * 64 + (i & 63)];
    __syncthreads();
    const int n = tid;                            // 0..255
    float as0=0,as1=0,as2=0,as3=0,as4=0,as5=0,as6=0,as7=0;
    float ar0=0,ar1=0,ar2=0,ar3=0,ar4=0,ar5=0,ar6=0,ar7=0;
    const float* w = rW0 + (size_t)n * 160;
    for (int d = 0; d < 64; d++) {
        float ws = w[d], wr = w[64 + d];
        as0 += Os[0][d]*ws; as1 += Os[1][d]*ws; as2 += Os[2][d]*ws; as3 += Os[3][d]*ws;
        as4 += Os[4][d]*ws; as5 += Os[5][d]*ws; as6 += Os[6][d]*ws; as7 += Os[7][d]*ws;
        ar0 += Os[0][d]*wr; ar1 += Os[1][d]*wr; ar2 += Os[2][d]*wr; ar3 += Os[3][d]*wr;
        ar4 += Os[4][d]*wr; ar5 += Os[5][d]*wr; ar6 += Os[6][d]*wr; ar7 += Os[7][d]*wr;
    }
    f16* ds = OWsT + ((size_t)b * 256 + n) * 128 + oc * 8;
    f16* dr = OWrT + ((size_t)b * 256 + n) * 128 + oc * 8;
    ds[0]=(f16)as0; ds[1]=(f16)as1; ds[2]=(f16)as2; ds[3]=(f16)as3;
    ds[4]=(f16)as4; ds[5]=(f16)as5; ds[6]=(f16)as6; ds[7]=(f16)as7;
    dr[0]=(f16)ar0; dr[1]=(f16)ar1; dr[2]=(f16)ar2; dr[3]=(f16)ar3;
    dr[4]=(f16)ar4; dr[5]=(f16)ar5; dr[6]=(f16)ar6; dr[7]=(f16)ar7;
}

// one MLP layer on swizzled LDS (r4-validated): M=64 rows, wave covers 32 cols
template<int KSTEPS, int K, int AS, int OS>
__device__ __forceinline__ void mlp64s(const f16* As, const f16* __restrict__ Wb,
                                       const float* __restrict__ bias, f16* Os,
                                       int n0, int l15, int lq)
{
    f32x4 acc[4][2] = {};
#pragma unroll
    for (int ks = 0; ks < KSTEPS; ks++) {
        f16x8 b0 = *(const f16x8*)(Wb + (size_t)(n0 + l15) * K + ks * 32 + (lq << 3));
        f16x8 b1 = *(const f16x8*)(Wb + (size_t)(n0 + 16 + l15) * K + ks * 32 + (lq << 3));
#pragma unroll
        for (int m = 0; m < 4; m++) {
            f16x8 af = *(const f16x8*)(As + swzi(m * 16 + l15, ks * 32 + (lq << 3), AS));
            acc[m][0] = MF(af, b0, acc[m][0]);
            acc[m][1] = MF(af, b1, acc[m][1]);
        }
    }
    float bv0 = bias[n0 + l15], bv1 = bias[n0 + 16 + l15];
#pragma unroll
    for (int m = 0; m < 4; m++) {
#pragma unroll
        for (int q = 0; q < 4; q++) {
            int row = m * 16 + (lq << 2) + q;
            Os[swzi(row, n0 + l15, OS)]      = (f16)fmaxf(acc[m][0][q] + bv0, 0.f);
            Os[swzi(row, n0 + 16 + l15, OS)] = (f16)fmaxf(acc[m][1][q] + bv1, 0.f);
        }
    }
}

// ------- fused relational: staged-RI fused L1 + L2 + L3 + global-A scatter; 72KB LDS -------
__global__ __launch_bounds__(512)
void krel9(const float* __restrict__ SR, const float* __restrict__ RRg,
           const float* __restrict__ RI,
           const f16* __restrict__ W0b, const f16* __restrict__ W1b,
           const f16* __restrict__ W2b,
           const float* __restrict__ rb0, const float* __restrict__ rb1,
           const float* __restrict__ rb2,
           const f16* __restrict__ OWsT, const f16* __restrict__ OWrT,
           float* __restrict__ er)
{
    __shared__ __align__(16) char smem[73728];
    f16* SRt = (f16*)(smem);            // [64][128] swz  (dead after L1)
    f16* RRt = (f16*)(smem + 16384);    // [64][128] swz  (dead after L1)
    f16* RIs = (f16*)(smem + 32768);    // [64][64] swz (cols 0..31 used), dead after L1
    f16* h1s = (f16*)(smem + 40960);    // [64][256] swz (dead after L2)
    f16* h2s = (f16*)(smem);            // [64][256] swz, aliases SRt+RRt
    f16* EtS = (f16*)(smem + 40960);    // [128][64] swz, aliases h1s

    const int b = blockIdx.y;
    const int grp = blockIdx.x;          // 32 groups
    const int tid = threadIdx.x;
    const int lane = tid & 63;
    const int wave = tid >> 6;
    const int l15 = lane & 15;
    const int lq = lane >> 4;
    const int k = tid & 7;

    f32x4 asc[8] = {};   // scatter accum: o-frag = wave, e-frags 0..7
    const size_t sbase = (size_t)b * NO_ * NR_;

    for (int t = grp; t < 254; t += 32) {
        const int r0 = t * 64;

        // ---- stage SR^T, RR^T ([r][o] swz) + RI ([r][c] swz) — conflict-free ----
#pragma unroll
        for (int half = 0; half < 2; half++) {
            int o = (tid >> 3) + (half << 6);
            const float* ps = SR + sbase + (size_t)o * NR_ + r0 + k;
            const float* pr = RRg + sbase + (size_t)o * NR_ + r0 + k;
#pragma unroll
            for (int j = 0; j < 8; j++) {
                float sv = ps[8 * j];
                float rv = pr[8 * j];
                int r = k + 8 * j;
                SRt[swzi(r, o, 128)] = (f16)sv;
                RRt[swzi(r, o, 128)] = (f16)rv;
            }
        }
        {
            int rr = tid >> 3, cc = (tid & 7) << 2;
            float4 vi = *(const float4*)(RI + ((size_t)b * NR_ + r0 + rr) * 32 + cc);
            f16x4 pI;
            pI[0] = (f16)vi.x; pI[1] = (f16)vi.y; pI[2] = (f16)vi.z; pI[3] = (f16)vi.w;
            *(f16x4*)(RIs + swzi(rr, cc, 64)) = pI;
        }
        __syncthreads();

        // ---- fused L1: h1 = relu(SR^T·OWs + RR^T·OWr + RI·W0i^T + b0) ----
        {
            f32x4 acc[4][2] = {};
            const int n0 = wave * 32;
            const f16* Bs = OWsT + ((size_t)b * 256 + n0 + l15) * 128 + (lq << 3);
            const f16* Br = OWrT + ((size_t)b * 256 + n0 + l15) * 128 + (lq << 3);
#pragma unroll
            for (int ks = 0; ks < 4; ks++) {
                f16x8 b0 = *(const f16x8*)(Bs + (ks << 5));
                f16x8 b1 = *(const f16x8*)(Bs + (ks << 5) + 2048);   // +16 rows * 128
#pragma unroll
                for (int m = 0; m < 4; m++) {
                    f16x8 af = *(const f16x8*)(SRt + swzi(m * 16 + l15, (ks << 5) + (lq << 3), 128));
                    acc[m][0] = MF(af, b0, acc[m][0]);
                    acc[m][1] = MF(af, b1, acc[m][1]);
                }
            }
#pragma unroll
            for (int ks = 0; ks < 4; ks++) {
                f16x8 b0 = *(const f16x8*)(Br + (ks << 5));
                f16x8 b1 = *(const f16x8*)(Br + (ks << 5) + 2048);
#pragma unroll
                for (int m = 0; m < 4; m++) {
                    f16x8 af = *(const f16x8*)(RRt + swzi(m * 16 + l15, (ks << 5) + (lq << 3), 128));
                    acc[m][0] = MF(af, b0, acc[m][0]);
                    acc[m][1] = MF(af, b1, acc[m][1]);
                }
            }
            {   // RI segment, K=32, A from LDS
                f16x8 b0 = *(const f16x8*)(W0b + (size_t)(n0 + l15) * 160 + 128 + (lq << 3));
                f16x8 b1 = *(const f16x8*)(W0b + (size_t)(n0 + 16 + l15) * 160 + 128 + (lq << 3));
#pragma unroll
                for (int m = 0; m < 4; m++) {
                    f16x8 af = *(const f16x8*)(RIs + swzi(m * 16 + l15, (lq << 3), 64));
                    acc[m][0] = MF(af, b0, acc[m][0]);
                    acc[m][1] = MF(af, b1, acc[m][1]);
                }
            }
            float bv0 = rb0[n0 + l15], bv1 = rb0[n0 + 16 + l15];
#pragma unroll
            for (int m = 0; m < 4; m++) {
#pragma unroll
                for (int q = 0; q < 4; q++) {
                    int row = m * 16 + (lq << 2) + q;
                    h1s[swzi(row, n0 + l15, 256)]      = (f16)fmaxf(acc[m][0][q] + bv0, 0.f);
                    h1s[swzi(row, n0 + 16 + l15, 256)] = (f16)fmaxf(acc[m][1][q] + bv1, 0.f);
                }
            }
        }
        __syncthreads();

        mlp64s<8, 256, 256, 256>(h1s, W1b, rb1, h2s, wave * 32, l15, lq);
        __syncthreads();

        // ---- layer3 -> effects^T [e][r] in LDS (swizzled) ----
        {
            const int e = (wave << 4) + l15;
            f32x4 acc[4] = {};
#pragma unroll
            for (int ks = 0; ks < 8; ks++) {
                f16x8 bf = *(const f16x8*)(W2b + (size_t)e * 256 + (ks << 5) + (lq << 3));
#pragma unroll
                for (int m = 0; m < 4; m++) {
                    f16x8 af = *(const f16x8*)(h2s + swzi(m * 16 + l15, (ks << 5) + (lq << 3), 256));
                    acc[m] = MF(af, bf, acc[m]);
                }
            }
            float bv = rb2[e];
#pragma unroll
            for (int m = 0; m < 4; m++) {
                f16x4 pk;
#pragma unroll
                for (int q = 0; q < 4; q++) pk[q] = (f16)fmaxf(acc[m][q] + bv, 0.f);
                *(f16x4*)(EtS + swzi(e, (m << 4) + (lq << 2), 64)) = pk;
            }
        }
        __syncthreads();

        // ---- scatter partial: asc[nf] += RR(global, L2-hot) x EtS, K = 64 ----
        // No barrier after: next-tile staging (SRt/RRt/RIs) is disjoint from EtS.
        {
            const int ow = wave << 4;
#pragma unroll
            for (int ks = 0; ks < 2; ks++) {
                const float* pa = RRg + sbase + (size_t)(ow + l15) * NR_ + r0 + (ks << 5) + (lq << 3);
                float4 a0 = *(const float4*)pa;
                float4 a1 = *(const float4*)(pa + 4);
                f16x8 af;
                af[0]=(f16)a0.x; af[1]=(f16)a0.y; af[2]=(f16)a0.z; af[3]=(f16)a0.w;
                af[4]=(f16)a1.x; af[5]=(f16)a1.y; af[6]=(f16)a1.z; af[7]=(f16)a1.w;
#pragma unroll
                for (int nf = 0; nf < 8; nf++) {
                    f16x8 bf = *(const f16x8*)(EtS + swzi((nf << 4) + l15, (ks << 5) + (lq << 3), 64));
                    asc[nf] = MF(af, bf, asc[nf]);
                }
            }
        }
    }

    // ---- commit scatter partials ----
    float* dst = er + ((size_t)b << 14);
#pragma unroll
    for (int nf = 0; nf < 8; nf++) {
        int e = (nf << 4) + l15;
#pragma unroll
        for (int q = 0; q < 4; q++) {
            int o = (wave << 4) + (lq << 2) + q;
            atomicAdd(dst + (size_t)o * 128 + e, asc[nf][q]);
        }
    }
}

// ---------------- object MLP, all-f32 VALU, f32 output ----------------
__global__ __launch_bounds__(256)
void kobj32(const float* __restrict__ objects, const float* __restrict__ er,
            const float* __restrict__ oW0, const float* __restrict__ oW1,
            const float* __restrict__ oW2,
            const float* __restrict__ ob0, const float* __restrict__ ob1,
            const float* __restrict__ ob2, float* __restrict__ out)
{
    __shared__ float ys[8][192];
    __shared__ float h1[8][256];
    __shared__ float h2[8][128];
    const int r0 = blockIdx.x * 8;        // 256 blocks x 8 rows = 2048 rows (b*128+o)
    const int tid = threadIdx.x;

    for (int c = tid; c < 8 * 192; c += 256) {
        int rr = c / 192, kk = c % 192;
        ys[rr][kk] = (kk < 64) ? objects[(size_t)(r0 + rr) * 64 + kk]
                               : er[(size_t)(r0 + rr) * 128 + (kk - 64)];
    }
    __syncthreads();
    for (int c = tid; c < 8 * 256; c += 256) {   // layer1: K=192, N=256
        int rr = c >> 8, n = c & 255;
        const float* w = oW0 + (size_t)n * 192;
        float s = ob0[n];
        for (int kk = 0; kk < 192; kk++) s += ys[rr][kk] * w[kk];
        h1[rr][n] = fmaxf(s, 0.f);
    }
    __syncthreads();
    for (int c = tid; c < 8 * 128; c += 256) {   // layer2: K=256, N=128
        int rr = c >> 7, n = c & 127;
        const float* w = oW1 + (size_t)n * 256;
        float s = ob1[n];
        for (int kk = 0; kk < 256; kk++) s += h1[rr][kk] * w[kk];
        h2[rr][n] = fmaxf(s, 0.f);
    }
    __syncthreads();
    for (int c = tid; c < 24; c += 256) {        // layer3: N=3
        int rr = c / 3, j = c % 3;
        const float* w = oW2 + j * 128;
        float s = ob2[j];
        for (int kk = 0; kk < 128; kk++) s += h2[rr][kk] * w[kk];
        out[(size_t)(r0 + rr) * 3 + j] = s;
    }
}

extern "C" void kernel_launch(void* const* d_in, const int* in_sizes, int n_in,
                              void* d_out, int out_size, void* d_ws, size_t ws_size,
                              hipStream_t stream)
{
    (void)in_sizes; (void)n_in; (void)out_size; (void)ws_size;
    const float* objects = (const float*)d_in[0];
    const float* SR  = (const float*)d_in[1];
    const float* RRg = (const float*)d_in[2];
    const float* RI  = (const float*)d_in[3];
    const float* rW0 = (const float*)d_in[4];
    const float* rb0 = (const float*)d_in[5];
    const float* rW1 = (const float*)d_in[6];
    const float* rb1 = (const float*)d_in[7];
    const float* rW2 = (const float*)d_in[8];
    const float* rb2 = (const float*)d_in[9];
    const float* oW0 = (const float*)d_in[10];
    const float* ob0 = (const float*)d_in[11];
    const float* oW1 = (const float*)d_in[12];
    const float* ob1 = (const float*)d_in[13];
    const float* oW2 = (const float*)d_in[14];
    const float* ob2 = (const float*)d_in[15];

    char* ws = (char*)d_ws;
    f16* W0b  = (f16*)(ws + 0);            // 81920 B
    f16* W1b  = (f16*)(ws + 81920);        // 131072 B
    f16* W2b  = (f16*)(ws + 212992);       // 65536 B
    f16* OWsT = (f16*)(ws + 278528);       // 1048576 B
    f16* OWrT = (f16*)(ws + 1327104);      // 1048576 B
    float* er = (float*)(ws + 2375680);    // 1048576 B  (total ~3.4 MB)

    hipLaunchKernelGGL(kprep, dim3(512), dim3(256), 0, stream,
                       rW0, rW1, rW2, W0b, W1b, W2b, er);
    hipLaunchKernelGGL(kow, dim3(16, 16), dim3(256), 0, stream,
                       objects, rW0, OWsT, OWrT);
    hipLaunchKernelGGL(krel9, dim3(32, 16), dim3(512), 0, stream,
                       SR, RRg, RI, W0b, W1b, W2b, rb0, rb1, rb2, OWsT, OWrT, er);
    hipLaunchKernelGGL(kobj32, dim3(256), dim3(256), 0, stream,
                       objects, er, oW0, oW1, oW2, ob0, ob1, ob2, (float*)d_out);
}

// Round 11
// 434.430 us; speedup vs baseline: 1.4525x; 1.0787x over previous
//
#include <hip/hip_runtime.h>

typedef _Float16 f16;
typedef _Float16 f16x8 __attribute__((ext_vector_type(8)));
typedef _Float16 f16x4 __attribute__((ext_vector_type(4)));
typedef float f32x4 __attribute__((ext_vector_type(4)));

#define NR_ 16256
#define NO_ 128
#define NB_ 16

__device__ __forceinline__ f32x4 MF(f16x8 a, f16x8 b, f32x4 c) {
    return __builtin_amdgcn_mfma_f32_16x16x32_f16(a, b, c, 0, 0, 0);
}

// 16B-block XOR swizzle (r4-validated): element (r,o) of [R][rs] f16 tile; rs/8 blocks, mult of 8.
__device__ __forceinline__ int swzi(int r, int o, int rs) {
    int cb = (o >> 3) ^ (r & 7);
    return r * rs + (cb << 3) + (o & 7);
}

// ---------------- prep: fp32 -> f16 weight copies + objects^T + er zero ----------------
__global__ void kprep(const float* __restrict__ rW0, const float* __restrict__ rW1,
                      const float* __restrict__ rW2, const float* __restrict__ objects,
                      f16* W0b, f16* W1b, f16* W2b, f16* OT, float* er)
{
    int i = blockIdx.x * 256 + threadIdx.x, n = gridDim.x * 256;
    for (int j = i; j < 40960; j += n) W0b[j] = (f16)rW0[j];
    for (int j = i; j < 65536; j += n) W1b[j] = (f16)rW1[j];
    for (int j = i; j < 32768; j += n) W2b[j] = (f16)rW2[j];
    for (int j = i; j < 131072; j += n) {
        int b = j >> 13, rem = j & 8191, o = rem >> 6, d = rem & 63;
        OT[((size_t)b << 13) + (d << 7) + o] = (f16)objects[j];  // OT[b][d][o]
    }
    for (int j = i; j < NB_ * 128 * 128; j += n) er[j] = 0.f;
}

// one MLP layer on swizzled LDS (r4-validated): M=64 rows, wave covers 32 cols
template<int KSTEPS, int K, int AS, int OS>
__device__ __forceinline__ void mlp64s(const f16* As, const f16* __restrict__ Wb,
                                       const float* __restrict__ bias, f16* Os,
                                       int n0, int l15, int lq)
{
    f32x4 acc[4][2] = {};
#pragma unroll
    for (int ks = 0; ks < KSTEPS; ks++) {
        f16x8 b0 = *(const f16x8*)(Wb + (size_t)(n0 + l15) * K + ks * 32 + (lq << 3));
        f16x8 b1 = *(const f16x8*)(Wb + (size_t)(n0 + 16 + l15) * K + ks * 32 + (lq << 3));
#pragma unroll
        for (int m = 0; m < 4; m++) {
            f16x8 af = *(const f16x8*)(As + swzi(m * 16 + l15, ks * 32 + (lq << 3), AS));
            acc[m][0] = MF(af, b0, acc[m][0]);
            acc[m][1] = MF(af, b1, acc[m][1]);
        }
    }
    float bv0 = bias[n0 + l15], bv1 = bias[n0 + 16 + l15];
#pragma unroll
    for (int m = 0; m < 4; m++) {
#pragma unroll
        for (int q = 0; q < 4; q++) {
            int row = m * 16 + (lq << 2) + q;
            Os[swzi(row, n0 + l15, OS)]      = (f16)fmaxf(acc[m][0][q] + bv0, 0.f);
            Os[swzi(row, n0 + 16 + l15, OS)] = (f16)fmaxf(acc[m][1][q] + bv1, 0.f);
        }
    }
}

// ---- fused relational: gather + 3-layer MLP + global-A scatter; 80KB LDS, swizzled ----
__global__ __launch_bounds__(512)
void krel10(const float* __restrict__ SR, const float* __restrict__ RRg,
            const float* __restrict__ RI,
            const f16* __restrict__ W0b, const f16* __restrict__ W1b,
            const f16* __restrict__ W2b,
            const float* __restrict__ rb0, const float* __restrict__ rb1,
            const float* __restrict__ rb2,
            const f16* __restrict__ OT, float* __restrict__ er)
{
    __shared__ __align__(16) char smem[81920];
    f16* OTs = (f16*)(smem);            // [64][128] swz  persistent (per block)
    f16* SRt = (f16*)(smem + 16384);    // [64][128] swz  (dead after gather)
    f16* RRt = (f16*)(smem + 32768);    // [64][128] swz  (dead after gather)
    f16* h1s = (f16*)(smem + 16384);    // [64][256] swz  aliases SRt+RRt (dead after L2)
    f16* EtS = (f16*)(smem + 16384);    // [128][64] swz  aliases h1s lower half
    f16* xs  = (f16*)(smem + 49152);    // [64][256] swz  (cols 0..159 used; dead after L1)
    f16* h2s = (f16*)(smem + 49152);    // [64][256] swz  aliases xs

    const int b = blockIdx.y;
    const int grp = blockIdx.x;          // 32 groups
    const int tid = threadIdx.x;
    const int lane = tid & 63;
    const int wave = tid >> 6;
    const int l15 = lane & 15;
    const int lq = lane >> 4;

    // stage O^T once per block (swizzled): OTs[d][o]
    for (int c = tid; c < 1024; c += 512) {
        int d = c >> 4, cb8 = (c & 15) << 3;
        f16x8 v = *(const f16x8*)(OT + ((size_t)b * 64 + d) * 128 + cb8);
        *(f16x8*)(OTs + swzi(d, cb8, 128)) = v;
    }

    f32x4 asc[8] = {};   // scatter accum: o-frag = wave, e-frags 0..7
    const size_t sbase = (size_t)b * NO_ * NR_;

    for (int t = grp; t < 254; t += 32) {
        const int r0 = t * 64;

        // ---- stage SR^T, RR^T ([r][o] swz) — r3 float4-load pattern ----
        for (int c = tid; c < 1024; c += 512) {
            int o = c >> 3, rh = (c & 7) << 3, ob = o >> 3, ol = o & 7;
            const float* ps = SR + sbase + (size_t)o * NR_ + r0 + rh;
            const float* pr = RRg + sbase + (size_t)o * NR_ + r0 + rh;
            float4 s0 = *(const float4*)ps, s1 = *(const float4*)(ps + 4);
            float4 q0 = *(const float4*)pr, q1 = *(const float4*)(pr + 4);
            f16* dS = SRt + rh * 128 + ol;
            f16* dR = RRt + rh * 128 + ol;
            dS[0*128 + ((ob^0)<<3)] = (f16)s0.x; dS[1*128 + ((ob^1)<<3)] = (f16)s0.y;
            dS[2*128 + ((ob^2)<<3)] = (f16)s0.z; dS[3*128 + ((ob^3)<<3)] = (f16)s0.w;
            dS[4*128 + ((ob^4)<<3)] = (f16)s1.x; dS[5*128 + ((ob^5)<<3)] = (f16)s1.y;
            dS[6*128 + ((ob^6)<<3)] = (f16)s1.z; dS[7*128 + ((ob^7)<<3)] = (f16)s1.w;
            dR[0*128 + ((ob^0)<<3)] = (f16)q0.x; dR[1*128 + ((ob^1)<<3)] = (f16)q0.y;
            dR[2*128 + ((ob^2)<<3)] = (f16)q0.z; dR[3*128 + ((ob^3)<<3)] = (f16)q0.w;
            dR[4*128 + ((ob^4)<<3)] = (f16)q1.x; dR[5*128 + ((ob^5)<<3)] = (f16)q1.y;
            dR[6*128 + ((ob^6)<<3)] = (f16)q1.z; dR[7*128 + ((ob^7)<<3)] = (f16)q1.w;
        }
        // ---- stage relation_info into x[:,128:160] (swz) ----
        {
            int rr = tid >> 3, cc = (tid & 7) << 2;
            float4 vi = *(const float4*)(RI + ((size_t)b * NR_ + r0 + rr) * 32 + cc);
            f16x4 pI;
            pI[0] = (f16)vi.x; pI[1] = (f16)vi.y; pI[2] = (f16)vi.z; pI[3] = (f16)vi.w;
            *(f16x4*)(xs + swzi(rr, 128 + cc, 256)) = pI;
        }
        __syncthreads();

        // ---- gather: waves 0-3 senders (x cols 0-63), waves 4-7 receivers (64-127) ----
        {
            const f16* At = (wave < 4) ? SRt : RRt;
            const int nf = wave & 3;
            const int xcol = (wave < 4) ? 0 : 64;
            f32x4 acc[4] = {};
#pragma unroll
            for (int ks = 0; ks < 4; ks++) {
                f16x8 bf = *(const f16x8*)(OTs + swzi(nf * 16 + l15, (ks << 5) + (lq << 3), 128));
#pragma unroll
                for (int m = 0; m < 4; m++) {
                    f16x8 af = *(const f16x8*)(At + swzi(m * 16 + l15, (ks << 5) + (lq << 3), 128));
                    acc[m] = MF(af, bf, acc[m]);
                }
            }
#pragma unroll
            for (int m = 0; m < 4; m++)
#pragma unroll
                for (int q = 0; q < 4; q++)
                    xs[swzi(m * 16 + (lq << 2) + q, xcol + nf * 16 + l15, 256)] = (f16)acc[m][q];
        }
        __syncthreads();

        mlp64s<5, 160, 256, 256>(xs, W0b, rb0, h1s, wave * 32, l15, lq);
        __syncthreads();
        mlp64s<8, 256, 256, 256>(h1s, W1b, rb1, h2s, wave * 32, l15, lq);
        __syncthreads();

        // ---- layer3 -> effects^T [e][r] in LDS (swizzled) ----
        {
            const int e = (wave << 4) + l15;
            f32x4 acc[4] = {};
#pragma unroll
            for (int ks = 0; ks < 8; ks++) {
                f16x8 bf = *(const f16x8*)(W2b + (size_t)e * 256 + (ks << 5) + (lq << 3));
#pragma unroll
                for (int m = 0; m < 4; m++) {
                    f16x8 af = *(const f16x8*)(h2s + swzi(m * 16 + l15, (ks << 5) + (lq << 3), 256));
                    acc[m] = MF(af, bf, acc[m]);
                }
            }
            float bv = rb2[e];
#pragma unroll
            for (int m = 0; m < 4; m++) {
                f16x4 pk;
#pragma unroll
                for (int q = 0; q < 4; q++) pk[q] = (f16)fmaxf(acc[m][q] + bv, 0.f);
                *(f16x4*)(EtS + swzi(e, (m << 4) + (lq << 2), 64)) = pk;
            }
        }
        __syncthreads();

        // ---- scatter partial: asc[nf] += RR(global, L2-hot) x EtS, K = 64 (r10-validated) ----
        {
            const int ow = wave << 4;
#pragma unroll
            for (int ks = 0; ks < 2; ks++) {
                const float* pa = RRg + sbase + (size_t)(ow + l15) * NR_ + r0 + (ks << 5) + (lq << 3);
                float4 a0 = *(const float4*)pa;
                float4 a1 = *(const float4*)(pa + 4);
                f16x8 af;
                af[0]=(f16)a0.x; af[1]=(f16)a0.y; af[2]=(f16)a0.z; af[3]=(f16)a0.w;
                af[4]=(f16)a1.x; af[5]=(f16)a1.y; af[6]=(f16)a1.z; af[7]=(f16)a1.w;
#pragma unroll
                for (int nf = 0; nf < 8; nf++) {
                    f16x8 bf = *(const f16x8*)(EtS + swzi((nf << 4) + l15, (ks << 5) + (lq << 3), 64));
                    asc[nf] = MF(af, bf, asc[nf]);
                }
            }
        }
        __syncthreads();   // EtS region is re-staged (SRt) next iteration
    }

    // ---- commit scatter partials ----
    float* dst = er + ((size_t)b << 14);
#pragma unroll
    for (int nf = 0; nf < 8; nf++) {
        int e = (nf << 4) + l15;
#pragma unroll
        for (int q = 0; q < 4; q++) {
            int o = (wave << 4) + (lq << 2) + q;
            atomicAdd(dst + (size_t)o * 128 + e, asc[nf][q]);
        }
    }
}

// ---------------- object MLP, all-f32 VALU, f32 output ----------------
__global__ __launch_bounds__(256)
void kobj32(const float* __restrict__ objects, const float* __restrict__ er,
            const float* __restrict__ oW0, const float* __restrict__ oW1,
            const float* __restrict__ oW2,
            const float* __restrict__ ob0, const float* __restrict__ ob1,
            const float* __restrict__ ob2, float* __restrict__ out)
{
    __shared__ float ys[8][192];
    __shared__ float h1[8][256];
    __shared__ float h2[8][128];
    const int r0 = blockIdx.x * 8;        // 256 blocks x 8 rows = 2048 rows (b*128+o)
    const int tid = threadIdx.x;

    for (int c = tid; c < 8 * 192; c += 256) {
        int rr = c / 192, kk = c % 192;
        ys[rr][kk] = (kk < 64) ? objects[(size_t)(r0 + rr) * 64 + kk]
                               : er[(size_t)(r0 + rr) * 128 + (kk - 64)];
    }
    __syncthreads();
    for (int c = tid; c < 8 * 256; c += 256) {   // layer1: K=192, N=256
        int rr = c >> 8, n = c & 255;
        const float* w = oW0 + (size_t)n * 192;
        float s = ob0[n];
        for (int kk = 0; kk < 192; kk++) s += ys[rr][kk] * w[kk];
        h1[rr][n] = fmaxf(s, 0.f);
    }
    __syncthreads();
    for (int c = tid; c < 8 * 128; c += 256) {   // layer2: K=256, N=128
        int rr = c >> 7, n = c & 127;
        const float* w = oW1 + (size_t)n * 256;
        float s = ob1[n];
        for (int kk = 0; kk < 256; kk++) s += h1[rr][kk] * w[kk];
        h2[rr][n] = fmaxf(s, 0.f);
    }
    __syncthreads();
    for (int c = tid; c < 24; c += 256) {        // layer3: N=3
        int rr = c / 3, j = c % 3;
        const float* w = oW2 + j * 128;
        float s = ob2[j];
        for (int kk = 0; kk < 128; kk++) s += h2[rr][kk] * w[kk];
        out[(size_t)(r0 + rr) * 3 + j] = s;
    }
}

extern "C" void kernel_launch(void* const* d_in, const int* in_sizes, int n_in,
                              void* d_out, int out_size, void* d_ws, size_t ws_size,
                              hipStream_t stream)
{
    (void)in_sizes; (void)n_in; (void)out_size; (void)ws_size;
    const float* objects = (const float*)d_in[0];
    const float* SR  = (const float*)d_in[1];
    const float* RRg = (const float*)d_in[2];
    const float* RI  = (const float*)d_in[3];
    const float* rW0 = (const float*)d_in[4];
    const float* rb0 = (const float*)d_in[5];
    const float* rW1 = (const float*)d_in[6];
    const float* rb1 = (const float*)d_in[7];
    const float* rW2 = (const float*)d_in[8];
    const float* rb2 = (const float*)d_in[9];
    const float* oW0 = (const float*)d_in[10];
    const float* ob0 = (const float*)d_in[11];
    const float* oW1 = (const float*)d_in[12];
    const float* ob1 = (const float*)d_in[13];
    const float* oW2 = (const float*)d_in[14];
    const float* ob2 = (const float*)d_in[15];

    char* ws = (char*)d_ws;
    f16* W0b = (f16*)(ws + 0);             // 81920 B
    f16* W1b = (f16*)(ws + 81920);         // 131072 B
    f16* W2b = (f16*)(ws + 212992);        // 65536 B
    f16* OT  = (f16*)(ws + 278528);        // 262144 B
    float* er = (float*)(ws + 540672);     // 1048576 B  (total ~1.6 MB)

    hipLaunchKernelGGL(kprep, dim3(512), dim3(256), 0, stream,
                       rW0, rW1, rW2, objects, W0b, W1b, W2b, OT, er);
    hipLaunchKernelGGL(krel10, dim3(32, 16), dim3(512), 0, stream,
                       SR, RRg, RI, W0b, W1b, W2b, rb0, rb1, rb2, OT, er);
    hipLaunchKernelGGL(kobj32, dim3(256), dim3(256), 0, stream,
                       objects, er, oW0, oW1, oW2, ob0, ob1, ob2, (float*)d_out);
}